// Round 8
// baseline (225.234 us; speedup 1.0000x reference)
//
#include <hip/hip_runtime.h>
#include <hip/hip_bf16.h>

// CrossAttention: B=4, C=256, H=W=64 -> N=M=4096, RC=32
// v15: concurrency-first attn (latency-bound diagnosis: v9 3 blk/CU ~40us
//      beat v10-v14 1-2 blk/CU ~50-56us regardless of bytes/LDS/barriers).
//  - n=16/block, full m, 256 thr (4 waves): grid 1024 = 4 blocks/CU =
//    4 independent barrier domains. No partials, no combine.
//  - PV: mfma_scale_f32_16x16x128_f8f6f4 (unit scales), 4/wave/iter,
//    slabs of 128 m, 32 iters. d-slice 64/wave.
//  - V stored as V^T rows: Vt[b][d][m] fp8 (fused_proj writes direct,
//    LDS shuffle dropped). V frag = 32 B contiguous per lane.
//  - P layout: 64 rows (row == reader lane) x 136 B stride: writer 2-way,
//    reader 4x ds_read_b64 2-way -> conflict-free class.
//  - dispatch mapping: same-CU quartet = 4 consecutive n-blocks of same b
//    (qs = bid>>8) -> shared V/K stream hits L1/L2 hot.
//  - counted lgkm barrier; V/K prefetch 1-2 slabs ahead stays in flight.

#define B_ 4
#define C_ 256
#define N_ 4096
#define M_ 4096
#define SCALE_ 0.17677669529663687f  // 1/sqrt(32)

typedef __bf16 bf16x8 __attribute__((ext_vector_type(8)));
typedef float f32x4 __attribute__((ext_vector_type(4)));
typedef int i32x8 __attribute__((ext_vector_type(8)));

#define AS1 __attribute__((address_space(1)))
#define AS3 __attribute__((address_space(3)))

static __device__ __forceinline__ unsigned short f2bf(float f) {
    unsigned int u = __float_as_uint(f);
    return (unsigned short)((u + 0x7fffu + ((u >> 16) & 1u)) >> 16);
}
static __device__ __forceinline__ unsigned bfpk(float a, float b) {
    return (unsigned)f2bf(a) | ((unsigned)f2bf(b) << 16);
}
// LDS-ordering barrier that does NOT drain vmcnt.
static __device__ __forceinline__ void p_barrier() {
    asm volatile("s_waitcnt lgkmcnt(0)" ::: "memory");
    __builtin_amdgcn_s_barrier();
    asm volatile("" ::: "memory");
}

// ---------------------------------------------------------------------------
// prep: weights -> bf16 MFMA fragment order. grid 40 x 256. (unchanged)
// ---------------------------------------------------------------------------
__global__ __launch_bounds__(256) void prep(
        const float* __restrict__ Wq, const float* __restrict__ Wk,
        const float* __restrict__ Wv, uint4* __restrict__ Wqf,
        uint4* __restrict__ Wkf, uint4* __restrict__ Wvf) {
    int bid = blockIdx.x, t = threadIdx.x;
    const float* W;
    uint4* dst;
    int frag;
    if (bid < 32)      { W = Wv; dst = Wvf; frag = (bid * 256 + t) >> 6; }
    else if (bid < 36) { W = Wq; dst = Wqf; frag = ((bid - 32) * 256 + t) >> 6; }
    else               { W = Wk; dst = Wkf; frag = ((bid - 36) * 256 + t) >> 6; }
    int lane = t & 63, low = lane & 15, q = lane >> 4;
    int fch = frag & 7, fr = frag >> 3;
    const float* wp = W + (size_t)(fr * 16 + low) * C_ + fch * 32 + q * 8;
    float4 w0 = *(const float4*)wp;
    float4 w1 = *(const float4*)(wp + 4);
    uint4 pk = {bfpk(w0.x, w0.y), bfpk(w0.z, w0.w),
                bfpk(w1.x, w1.y), bfpk(w1.z, w1.w)};
    dst[(size_t)frag * 64 + lane] = pk;
}

// ---------------------------------------------------------------------------
// Fused transpose + projections. grid 512 x 256.
// v6 + V now written DIRECTLY as V^T rows: Vt[b][d][m] fp8 (no LDS shuffle).
// ---------------------------------------------------------------------------
__global__ __launch_bounds__(256, 2) void fused_proj(
        const float* __restrict__ x, const float* __restrict__ ctx,
        const uint4* __restrict__ Wqf, const uint4* __restrict__ Wkf,
        const uint4* __restrict__ Wvf,
        const float* __restrict__ bq, const float* __restrict__ bk,
        const float* __restrict__ bv,
        unsigned short* __restrict__ Qf, unsigned short* __restrict__ Kf,
        unsigned char* __restrict__ Vt) {
    __shared__ unsigned short X[64][264];
    __shared__ unsigned short Pl[4][16 * 40];

    int bid = blockIdx.x;
    bool isX = bid >= 256;
    int lb = bid & 255;
    int b = lb >> 6, pt64 = lb & 63;
    const float* __restrict__ in = (isX ? x : ctx) + (size_t)b * C_ * N_ + pt64 * 64;
    int t = threadIdx.x, wg = t >> 6, lane = t & 63;
    int low = lane & 15, q = lane >> 4;

    {
        int pL = lane;
        const float* s0 = in + pL;
#pragma unroll
        for (int ct = 0; ct < 4; ct++) {
            const float* s2 = s0 + (size_t)(ct * 64 + wg * 16) * N_;
            float v[16];
#pragma unroll
            for (int k = 0; k < 16; k++) v[k] = s2[(size_t)k * N_];
#pragma unroll
            for (int k = 0; k < 16; k += 2)
                *(unsigned*)&X[pL][ct * 64 + wg * 16 + k] = bfpk(v[k], v[k + 1]);
        }
    }
    __syncthreads();

    {
        const uint4* __restrict__ Wf = isX ? Wqf : Wkf;
        const float* __restrict__ bias = isX ? bq : bk;
        unsigned short* __restrict__ dst = isX ? Qf : Kf;
        bf16x8 xf[8];
#pragma unroll
        for (int ch = 0; ch < 8; ch++)
            xf[ch] = *(const bf16x8*)&X[wg * 16 + low][ch * 32 + q * 8];
        const f32x4 zero = {0.f, 0.f, 0.f, 0.f};
        f32x4 acc[2] = {zero, zero};
#pragma unroll
        for (int rt = 0; rt < 2; rt++)
#pragma unroll
            for (int ch = 0; ch < 8; ch++) {
                uint4 wv = Wf[(rt * 8 + ch) * 64 + lane];
                acc[rt] = __builtin_amdgcn_mfma_f32_16x16x32_bf16(
                    __builtin_bit_cast(bf16x8, wv), xf[ch], acc[rt], 0, 0, 0);
            }
        unsigned short* Pw = &Pl[wg][0];
#pragma unroll
        for (int rt = 0; rt < 2; rt++) {
            float b0 = bias[rt * 16 + q * 4 + 0], b1 = bias[rt * 16 + q * 4 + 1];
            float b2 = bias[rt * 16 + q * 4 + 2], b3 = bias[rt * 16 + q * 4 + 3];
            uint2 pk = {bfpk(acc[rt][0] + b0, acc[rt][1] + b1),
                        bfpk(acc[rt][2] + b2, acc[rt][3] + b3)};
            *(uint2*)(Pw + low * 40 + rt * 16 + q * 4) = pk;
        }
        uint4 frag = *(const uint4*)(Pw + low * 40 + q * 8);
        ((uint4*)dst)[((size_t)b * 256 + pt64 * 4 + wg) * 64 + lane] = frag;
    }

    if (!isX) {
        int mstep = wg >> 1, dh = wg & 1;
        bf16x8 vfr[2][8];
#pragma unroll
        for (int mt = 0; mt < 2; mt++)
#pragma unroll
            for (int ch = 0; ch < 8; ch++)
                vfr[mt][ch] = *(const bf16x8*)&X[mstep * 32 + mt * 16 + low][ch * 32 + q * 8];
        int msg = pt64 * 2 + mstep;            // m-32-group index (0..127)
        const f32x4 zero = {0.f, 0.f, 0.f, 0.f};
#pragma unroll
        for (int dt8 = 0; dt8 < 8; dt8++) {
            int dt = dh * 8 + dt8;
            f32x4 a0 = zero, a1 = zero;
#pragma unroll
            for (int ch = 0; ch < 8; ch++) {
                uint4 wv = Wvf[(dt * 8 + ch) * 64 + lane];
                bf16x8 wfr = __builtin_bit_cast(bf16x8, wv);
                a0 = __builtin_amdgcn_mfma_f32_16x16x32_bf16(vfr[0][ch], wfr, a0, 0, 0, 0);
                a1 = __builtin_amdgcn_mfma_f32_16x16x32_bf16(vfr[1][ch], wfr, a1, 0, 0, 0);
            }
            float bb = bv[dt * 16 + low];
            unsigned w0 = __builtin_amdgcn_cvt_pk_fp8_f32(a0[0] + bb, a0[1] + bb, 0, false);
            w0 = __builtin_amdgcn_cvt_pk_fp8_f32(a0[2] + bb, a0[3] + bb, w0, true);
            unsigned w1 = __builtin_amdgcn_cvt_pk_fp8_f32(a1[0] + bb, a1[1] + bb, 0, false);
            w1 = __builtin_amdgcn_cvt_pk_fp8_f32(a1[2] + bb, a1[3] + bb, w1, true);
            // V^T row d = dt*16+low, m = msg*32 + mt*16 + q*4 + 0..3
            unsigned* vr = (unsigned*)(Vt + ((size_t)(b * 256 + dt * 16 + low)) * 4096
                                          + msg * 32 + q * 4);
            vr[0] = w0;        // mt = 0
            vr[4] = w1;        // mt = 1 (+16 B)
        }
    }
}

// ---------------------------------------------------------------------------
// Flash attention v15. grid 1024 x 256 (4 blocks/CU, 4 waves each).
// Block = (b, g): 16 n rows (ONE q-tile), full m (32 slabs of 128).
// Per wave per iter: QK 2 m-16-tiles (2 mfma 16x16x32 bf16 + 8 exp + pack);
// PV d-slice [wg*64, wg*64+64): 4 mfma_scale 16x16x128 f8f6f4.
// P LDS: 64 rows (row = (m>>5)*16 + n == reader lane) x 136 B, ping-pong.
// V/K frags global->VGPR, prefetched 1-2 slabs ahead; lgkm-only barrier.
// Epilogue fused: out = gamma*O/l + x (no LDS transpose needed: C-layout
// rows = d, cols = n already).
// ---------------------------------------------------------------------------
__global__ __launch_bounds__(256, 4) void attn(
        const unsigned short* __restrict__ Qf, const unsigned short* __restrict__ Kf,
        const unsigned char* __restrict__ Vt, const float* __restrict__ x,
        const float* __restrict__ gamma, float* __restrict__ out) {
    __shared__ __align__(16) unsigned char Pb[2][64 * 136];  // 17408 B
    __shared__ float l_sh[4][16];

    // mapping: same-CU quartet (qs=0..3) = 4 consecutive n-blocks of same b.
    int bid = blockIdx.x;
    int xcd = bid & 7, cu5 = (bid >> 3) & 31, qs = bid >> 8;
    int b = xcd >> 1;
    int g = ((((xcd & 1) << 5) | cu5) << 2) | qs;   // 0..255; n0 = g*16

    int wg = threadIdx.x >> 6, lane = threadIdx.x & 63;
    int q = lane >> 4, low = lane & 15;

    const uint4* Qp = (const uint4*)Qf;
    const uint4* Kp = (const uint4*)Kf + (size_t)b * 256 * 64;
    // V^T row base for this lane: d = wg*64 + dd*16 + low, k-group q
    const unsigned char* Vrow = Vt + ((size_t)(b * 256 + wg * 64 + low)) * 4096 + q * 32;

    bf16x8 qa = __builtin_bit_cast(bf16x8, Qp[(size_t)(b * 256 + g) * 64 + lane]);

    f32x4 acc[4];                                   // [dd]: O[d16][n16]
#pragma unroll
    for (int dd = 0; dd < 4; dd++) acc[dd] = (f32x4){0.f, 0.f, 0.f, 0.f};
    float lacc = 0.f;
    const f32x4 zero = {0.f, 0.f, 0.f, 0.f};

    // ---- prologue: S(0) -> P(0); kv <- K(1); vf <- V(0) ----
    uint4 kv[2];
    f32x4 s[2];
#pragma unroll
    for (int u = 0; u < 2; u++)
        kv[u] = Kp[(size_t)(wg * 2 + u) * 64 + lane];
#pragma unroll
    for (int u = 0; u < 2; u++)
        s[u] = __builtin_amdgcn_mfma_f32_16x16x32_bf16(
            __builtin_bit_cast(bf16x8, kv[u]), qa, zero, 0, 0, 0);
#pragma unroll
    for (int u = 0; u < 2; u++)
        kv[u] = Kp[(size_t)(8 + wg * 2 + u) * 64 + lane];
    {
        // P row = wg*16 + low (both u land in the same row), byte = u*16+q*4
        unsigned char* Pw = &Pb[0][0] + (wg * 16 + low) * 136 + q * 4;
#pragma unroll
        for (int u = 0; u < 2; u++) {
            float p0 = __expf(s[u][0] * SCALE_), p1 = __expf(s[u][1] * SCALE_);
            float p2 = __expf(s[u][2] * SCALE_), p3 = __expf(s[u][3] * SCALE_);
            lacc += p0 + p1 + p2 + p3;
            unsigned w = __builtin_amdgcn_cvt_pk_fp8_f32(p0, p1, 0, false);
            w = __builtin_amdgcn_cvt_pk_fp8_f32(p2, p3, w, true);
            *(unsigned*)(Pw + u * 16) = w;
        }
    }
    i32x8 vf[4];
#pragma unroll
    for (int dd = 0; dd < 4; dd++)
        vf[dd] = *(const i32x8*)(Vrow + (size_t)dd * 65536);
    p_barrier();

    // ---- main loop: 32 slabs of 128 m ----
    for (int i = 0; i < 32; i++) {
        int cur = i & 1, nxt = cur ^ 1;
        bool hn = (i + 1 < 32);

        // V(i+1) prefetch (stays in flight across the barrier)
        i32x8 vfn[4];
        if (hn) {
#pragma unroll
            for (int dd = 0; dd < 4; dd++)
                vfn[dd] = *(const i32x8*)(Vrow + (size_t)dd * 65536 + (i + 1) * 128);
        }

        // QK(i+1) from preloaded kv; refill kv for slab i+2
        if (hn) {
#pragma unroll
            for (int u = 0; u < 2; u++)
                s[u] = __builtin_amdgcn_mfma_f32_16x16x32_bf16(
                    __builtin_bit_cast(bf16x8, kv[u]), qa, zero, 0, 0, 0);
            if (i + 2 < 32) {
#pragma unroll
                for (int u = 0; u < 2; u++)
                    kv[u] = Kp[(size_t)((i + 2) * 8 + wg * 2 + u) * 64 + lane];
            }
        }

        // ---- PV(i): acc[dd] += V^T P^T (16x16x128, unit scales) ----
        {
            // B-frag: row = lane (n = lane&15, m-group = lane>>4), 32 B
            const unsigned char* pr = &Pb[cur][0] + lane * 136;
            i32x8 pf;
            long* pq = (long*)&pf;
#pragma unroll
            for (int j = 0; j < 4; j++)
                pq[j] = *(const long*)(pr + j * 8);
#pragma unroll
            for (int dd = 0; dd < 4; dd++)
                acc[dd] = __builtin_amdgcn_mfma_scale_f32_16x16x128_f8f6f4(
                    vf[dd], pf, acc[dd], 0, 0, 0, 127, 0, 127);
        }

        // pack P(i+1)
        if (hn) {
            unsigned char* Pw = &Pb[nxt][0] + (wg * 16 + low) * 136 + q * 4;
#pragma unroll
            for (int u = 0; u < 2; u++) {
                float p0 = __expf(s[u][0] * SCALE_), p1 = __expf(s[u][1] * SCALE_);
                float p2 = __expf(s[u][2] * SCALE_), p3 = __expf(s[u][3] * SCALE_);
                lacc += p0 + p1 + p2 + p3;
                unsigned w = __builtin_amdgcn_cvt_pk_fp8_f32(p0, p1, 0, false);
                w = __builtin_amdgcn_cvt_pk_fp8_f32(p2, p3, w, true);
                *(unsigned*)(Pw + u * 16) = w;
            }
#pragma unroll
            for (int dd = 0; dd < 4; dd++) vf[dd] = vfn[dd];
        }
        p_barrier();
    }

    // ---- l: reduce across q-groups, publish per (wave, n) ----
    lacc += __shfl_xor(lacc, 16, 64);
    lacc += __shfl_xor(lacc, 32, 64);
    if (lane < 16)
        l_sh[wg][low] = lacc;
    __syncthreads();

    // ---- fused epilogue: out[b][d][g*16+low] = gamma*O/l + x ----
    // C layout (16x16): col = lane&15 = n, row = q*4 + r = d-within-16.
    {
        float gm = gamma[0];
        float l = l_sh[0][low] + l_sh[1][low] + l_sh[2][low] + l_sh[3][low];
        float rinv = gm / l;
#pragma unroll
        for (int dd = 0; dd < 4; dd++) {
            int d = wg * 64 + dd * 16 + q * 4;
#pragma unroll
            for (int r = 0; r < 4; r++) {
                size_t idx = ((size_t)(b * 256 + d + r)) * 4096 + g * 16 + low;
                out[idx] = acc[dd][r] * rinv + x[idx];
            }
        }
    }
}

// ---------------------------------------------------------------------------
extern "C" void kernel_launch(void* const* d_in, const int* in_sizes, int n_in,
                              void* d_out, int out_size, void* d_ws, size_t ws_size,
                              hipStream_t stream) {
    const float* x     = (const float*)d_in[0];
    const float* ctx   = (const float*)d_in[1];
    const float* Wq    = (const float*)d_in[2];
    const float* bq    = (const float*)d_in[3];
    const float* Wk    = (const float*)d_in[4];
    const float* bk    = (const float*)d_in[5];
    const float* Wv    = (const float*)d_in[6];
    const float* bv    = (const float*)d_in[7];
    const float* gamma = (const float*)d_in[8];
    float* out = (float*)d_out;

    // ws: Qf 1M | Kf 1M | Vt 4M | Wqf/Wkf 16K | Wvf 128K
    unsigned short* Qf = (unsigned short*)d_ws;
    unsigned short* Kf = Qf + (size_t)B_ * N_ * 32;
    unsigned char*  Vt = (unsigned char*)(Kf + (size_t)B_ * M_ * 32);
    uint4* Wqf = (uint4*)(Vt + (size_t)B_ * M_ * C_);
    uint4* Wkf = Wqf + 16 * 64;
    uint4* Wvf = Wkf + 16 * 64;

    prep<<<40, 256, 0, stream>>>(Wq, Wk, Wv, Wqf, Wkf, Wvf);
    fused_proj<<<512, 256, 0, stream>>>(x, ctx, Wqf, Wkf, Wvf, bq, bk, bv, Qf, Kf, Vt);
    attn<<<1024, 256, 0, stream>>>(Qf, Kf, Vt, x, gamma, out);
}

// Round 9
// 147.922 us; speedup vs baseline: 1.5227x; 1.5227x over previous
//
#include <hip/hip_runtime.h>
#include <hip/hip_bf16.h>

// CrossAttention: B=4, C=256, H=W=64 -> N=M=4096, RC=32
// v16: v10 (champion, 139.6us) + critical-chain cut in attn.
//  Diagnosis: every prior version issued the V load for slab i+1 and
//  WAITED on it inside the same barrier interval (the vfc=vfn register
//  copy forces the s_waitcnt). Chain/iter ~1900cyc = V round trip (~600)
//  + QK/exp/pack (~300) + PV + barrier; invariant to occupancy/LDS/bytes,
//  matching v10-v13 all ~50us with all pipes <30% busy.
//  Fix 1: copy-free V double-buffer — unroll x2, named bufs vA/vB; load
//  for slab j+2 issued into the just-consumed buffer AFTER PV(j) reads
//  it; first waited on two barrier intervals later.
//  Fix 2: P-pack (exp chain) moved BEFORE PV — post-PV tail is just the
//  V-load issue + barrier.
//  Everything else verbatim v10.

#define B_ 4
#define C_ 256
#define N_ 4096
#define M_ 4096
#define SCALE_ 0.17677669529663687f  // 1/sqrt(32)

typedef __bf16 bf16x8 __attribute__((ext_vector_type(8)));
typedef float f32x4 __attribute__((ext_vector_type(4)));
typedef float f32x16 __attribute__((ext_vector_type(16)));
typedef int i32x8 __attribute__((ext_vector_type(8)));

#define AS1 __attribute__((address_space(1)))
#define AS3 __attribute__((address_space(3)))

static __device__ __forceinline__ unsigned short f2bf(float f) {
    unsigned int u = __float_as_uint(f);
    return (unsigned short)((u + 0x7fffu + ((u >> 16) & 1u)) >> 16);
}
static __device__ __forceinline__ unsigned bfpk(float a, float b) {
    return (unsigned)f2bf(a) | ((unsigned)f2bf(b) << 16);
}
// LDS-ordering barrier that does NOT drain vmcnt.
static __device__ __forceinline__ void p_barrier() {
    asm volatile("s_waitcnt lgkmcnt(0)" ::: "memory");
    __builtin_amdgcn_s_barrier();
    asm volatile("" ::: "memory");
}

// ---------------------------------------------------------------------------
// prep: weights -> bf16 MFMA fragment order. grid 40 x 256. (unchanged)
// ---------------------------------------------------------------------------
__global__ __launch_bounds__(256) void prep(
        const float* __restrict__ Wq, const float* __restrict__ Wk,
        const float* __restrict__ Wv, uint4* __restrict__ Wqf,
        uint4* __restrict__ Wkf, uint4* __restrict__ Wvf) {
    int bid = blockIdx.x, t = threadIdx.x;
    const float* W;
    uint4* dst;
    int frag;
    if (bid < 32)      { W = Wv; dst = Wvf; frag = (bid * 256 + t) >> 6; }
    else if (bid < 36) { W = Wq; dst = Wqf; frag = ((bid - 32) * 256 + t) >> 6; }
    else               { W = Wk; dst = Wkf; frag = ((bid - 36) * 256 + t) >> 6; }
    int lane = t & 63, low = lane & 15, q = lane >> 4;
    int fch = frag & 7, fr = frag >> 3;
    const float* wp = W + (size_t)(fr * 16 + low) * C_ + fch * 32 + q * 8;
    float4 w0 = *(const float4*)wp;
    float4 w1 = *(const float4*)(wp + 4);
    uint4 pk = {bfpk(w0.x, w0.y), bfpk(w0.z, w0.w),
                bfpk(w1.x, w1.y), bfpk(w1.z, w1.w)};
    dst[(size_t)frag * 64 + lane] = pk;
}

// ---------------------------------------------------------------------------
// Fused transpose + projections. grid 512 x 256. (verbatim v10)
// ---------------------------------------------------------------------------
__global__ __launch_bounds__(256, 2) void fused_proj(
        const float* __restrict__ x, const float* __restrict__ ctx,
        const uint4* __restrict__ Wqf, const uint4* __restrict__ Wkf,
        const uint4* __restrict__ Wvf,
        const float* __restrict__ bq, const float* __restrict__ bk,
        const float* __restrict__ bv,
        unsigned short* __restrict__ Qf, unsigned short* __restrict__ Kf,
        unsigned char* __restrict__ Vf) {
    __shared__ unsigned short X[64][264];
    __shared__ unsigned short Pl[4][16 * 40];
    __shared__ unsigned char  Vw[4][16 * 40];

    int bid = blockIdx.x;
    bool isX = bid >= 256;
    int lb = bid & 255;
    int b = lb >> 6, pt64 = lb & 63;
    const float* __restrict__ in = (isX ? x : ctx) + (size_t)b * C_ * N_ + pt64 * 64;
    int t = threadIdx.x, wg = t >> 6, lane = t & 63;
    int low = lane & 15, q = lane >> 4;

    {
        int pL = lane;
        const float* s0 = in + pL;
#pragma unroll
        for (int ct = 0; ct < 4; ct++) {
            const float* s2 = s0 + (size_t)(ct * 64 + wg * 16) * N_;
            float v[16];
#pragma unroll
            for (int k = 0; k < 16; k++) v[k] = s2[(size_t)k * N_];
#pragma unroll
            for (int k = 0; k < 16; k += 2)
                *(unsigned*)&X[pL][ct * 64 + wg * 16 + k] = bfpk(v[k], v[k + 1]);
        }
    }
    __syncthreads();

    {
        const uint4* __restrict__ Wf = isX ? Wqf : Wkf;
        const float* __restrict__ bias = isX ? bq : bk;
        unsigned short* __restrict__ dst = isX ? Qf : Kf;
        bf16x8 xf[8];
#pragma unroll
        for (int ch = 0; ch < 8; ch++)
            xf[ch] = *(const bf16x8*)&X[wg * 16 + low][ch * 32 + q * 8];
        const f32x4 zero = {0.f, 0.f, 0.f, 0.f};
        f32x4 acc[2] = {zero, zero};
#pragma unroll
        for (int rt = 0; rt < 2; rt++)
#pragma unroll
            for (int ch = 0; ch < 8; ch++) {
                uint4 wv = Wf[(rt * 8 + ch) * 64 + lane];
                acc[rt] = __builtin_amdgcn_mfma_f32_16x16x32_bf16(
                    __builtin_bit_cast(bf16x8, wv), xf[ch], acc[rt], 0, 0, 0);
            }
        unsigned short* Pw = &Pl[wg][0];
#pragma unroll
        for (int rt = 0; rt < 2; rt++) {
            float b0 = bias[rt * 16 + q * 4 + 0], b1 = bias[rt * 16 + q * 4 + 1];
            float b2 = bias[rt * 16 + q * 4 + 2], b3 = bias[rt * 16 + q * 4 + 3];
            uint2 pk = {bfpk(acc[rt][0] + b0, acc[rt][1] + b1),
                        bfpk(acc[rt][2] + b2, acc[rt][3] + b3)};
            *(uint2*)(Pw + low * 40 + rt * 16 + q * 4) = pk;
        }
        uint4 frag = *(const uint4*)(Pw + low * 40 + q * 8);
        ((uint4*)dst)[((size_t)b * 256 + pt64 * 4 + wg) * 64 + lane] = frag;
    }

    if (!isX) {
        int mstep = wg >> 1, dh = wg & 1;
        bf16x8 vfr[2][8];
#pragma unroll
        for (int mt = 0; mt < 2; mt++)
#pragma unroll
            for (int ch = 0; ch < 8; ch++)
                vfr[mt][ch] = *(const bf16x8*)&X[mstep * 32 + mt * 16 + low][ch * 32 + q * 8];
        unsigned char* Vv = &Vw[wg][0];
        int msg = pt64 * 2 + mstep;
        const f32x4 zero = {0.f, 0.f, 0.f, 0.f};
#pragma unroll
        for (int dt8 = 0; dt8 < 8; dt8++) {
            int dt = dh * 8 + dt8;
            f32x4 a0 = zero, a1 = zero;
#pragma unroll
            for (int ch = 0; ch < 8; ch++) {
                uint4 wv = Wvf[(dt * 8 + ch) * 64 + lane];
                bf16x8 wfr = __builtin_bit_cast(bf16x8, wv);
                a0 = __builtin_amdgcn_mfma_f32_16x16x32_bf16(vfr[0][ch], wfr, a0, 0, 0, 0);
                a1 = __builtin_amdgcn_mfma_f32_16x16x32_bf16(vfr[1][ch], wfr, a1, 0, 0, 0);
            }
            float bb = bv[dt * 16 + low];
            unsigned w0 = __builtin_amdgcn_cvt_pk_fp8_f32(a0[0] + bb, a0[1] + bb, 0, false);
            w0 = __builtin_amdgcn_cvt_pk_fp8_f32(a0[2] + bb, a0[3] + bb, w0, true);
            unsigned w1 = __builtin_amdgcn_cvt_pk_fp8_f32(a1[0] + bb, a1[1] + bb, 0, false);
            w1 = __builtin_amdgcn_cvt_pk_fp8_f32(a1[2] + bb, a1[3] + bb, w1, true);
            *(unsigned*)(Vv + low * 40 + q * 4) = w0;
            *(unsigned*)(Vv + low * 40 + 16 + q * 4) = w1;
            uint2 fr = *(const uint2*)(Vv + low * 40 + q * 8);
            ((uint2*)Vf)[(((size_t)b * 128 + msg) * 16 + dt) * 64 + lane] = fr;
        }
    }
}

// ---------------------------------------------------------------------------
// Flash attention v16. grid 256 x 512 (8 waves). Block = (b, g): 64 n rows,
// ALL 4096 m (64 slabs of 64). Waves 0-3: QK^T + softmax + P-pack for
// q-tile = wave. All 8 waves: PV d-slice [w*32, w*32+32) via
// mfma_scale_f32_32x32x64_f8f6f4 (unit scales).
// Copy-free V pipeline: unroll x2, vA/vB named buffers, V(j+2) issued into
// the just-consumed buffer after PV(j); waited 2 barrier intervals later.
// P-pack for slab j+1 runs BEFORE PV(j) (different LDS buffer).
// ---------------------------------------------------------------------------
__global__ __launch_bounds__(512, 2) void attn(
        const unsigned short* __restrict__ Qf, const unsigned short* __restrict__ Kf,
        const unsigned char* __restrict__ Vf, const float* __restrict__ x,
        const float* __restrict__ gamma, float* __restrict__ out) {
    __shared__ __align__(16) unsigned char Pb[2][4][16 * 80];  // 10240 B
    __shared__ float l_sh[64];
    __shared__ unsigned Ot[64 * 129];                          // 33024 B

    // bijective swizzle: XCD pair {2b,2b+1} hosts all 64 blocks of b.
    int bid = blockIdx.x;
    int xcd = bid & 7, tq = bid >> 3;
    int b = xcd >> 1;
    int g = ((xcd & 1) << 5) + tq;         // 0..63; n0 = g*64

    int wave = threadIdx.x >> 6, lane = threadIdx.x & 63;
    int q = lane >> 4, low = lane & 15;
    int hi = lane >> 5;                    // m-half selector
    int dsel = q & 1;                      // tile-parity selector
    int l31 = lane & 31;
    bool isQK = wave < 4;

    const uint4* Qp = (const uint4*)Qf;
    const uint4* Kp = (const uint4*)Kf + (size_t)b * 256 * 64;
    const uint2* Vq = (const uint2*)(Vf + (size_t)b * 1048576) + (size_t)hi * 1024 + low;
    int dt = wave * 2 + dsel;              // d-tile-of-16 (0..15)

    bf16x8 qa;
    if (isQK)
        qa = __builtin_bit_cast(bf16x8, Qp[(size_t)(b * 256 + g * 4 + wave) * 64 + lane]);

    f32x16 acc2[2];                        // [tp]: O^T 32n x 32d tiles
    acc2[0] = (f32x16)(0.f);
    acc2[1] = (f32x16)(0.f);
    float lacc = 0.f;
    const f32x4 zero = {0.f, 0.f, 0.f, 0.f};

    uint4 kv[4];
    f32x4 s[4];
    i32x8 vA, vB;

    // ---- prologue: S(0) -> P(0); kv <- K(1); issue V(0)->vA, V(1)->vB ----
    {
        long* dqw = (long*)&vA;
#pragma unroll
        for (int ss = 0; ss < 4; ss++)
            dqw[ss] = *(const long*)(Vq + dt * 64 + ss * 16);
        long* dqx = (long*)&vB;
#pragma unroll
        for (int ss = 0; ss < 4; ss++)
            dqx[ss] = *(const long*)(Vq + 2048 + dt * 64 + ss * 16);
    }
    if (isQK) {
#pragma unroll
        for (int u = 0; u < 4; u++)
            kv[u] = Kp[(size_t)u * 64 + lane];
#pragma unroll
        for (int u = 0; u < 4; u++)
            s[u] = __builtin_amdgcn_mfma_f32_16x16x32_bf16(
                __builtin_bit_cast(bf16x8, kv[u]), qa, zero, 0, 0, 0);
#pragma unroll
        for (int u = 0; u < 4; u++)
            kv[u] = Kp[(size_t)(4 + u) * 64 + lane];
        unsigned char* Pw = &Pb[0][wave][0];
#pragma unroll
        for (int u = 0; u < 4; u++) {
            float p0 = __expf(s[u][0] * SCALE_), p1 = __expf(s[u][1] * SCALE_);
            float p2 = __expf(s[u][2] * SCALE_), p3 = __expf(s[u][3] * SCALE_);
            lacc += p0 + p1 + p2 + p3;
            unsigned w = __builtin_amdgcn_cvt_pk_fp8_f32(p0, p1, 0, false);
            w = __builtin_amdgcn_cvt_pk_fp8_f32(p2, p3, w, true);
            *(unsigned*)(Pw + low * 80 + u * 16 + q * 4) = w;
        }
    }
    p_barrier();

    // ---- main loop: unroll x2, slabs j and j+1 ----
    auto step = [&](int j, i32x8& Vuse) {
        // QK(j+1) + pack P(j+1) BEFORE PV(j) (writes the other P buffer)
        if (isQK && j + 1 < 64) {
#pragma unroll
            for (int u = 0; u < 4; u++)
                s[u] = __builtin_amdgcn_mfma_f32_16x16x32_bf16(
                    __builtin_bit_cast(bf16x8, kv[u]), qa, zero, 0, 0, 0);
            if (j + 2 < 64) {
#pragma unroll
                for (int u = 0; u < 4; u++)
                    kv[u] = Kp[(size_t)((j + 2) * 4 + u) * 64 + lane];
            }
            unsigned char* Pw = &Pb[(j + 1) & 1][wave][0];
#pragma unroll
            for (int u = 0; u < 4; u++) {
                float p0 = __expf(s[u][0] * SCALE_), p1 = __expf(s[u][1] * SCALE_);
                float p2 = __expf(s[u][2] * SCALE_), p3 = __expf(s[u][3] * SCALE_);
                lacc += p0 + p1 + p2 + p3;
                unsigned w = __builtin_amdgcn_cvt_pk_fp8_f32(p0, p1, 0, false);
                w = __builtin_amdgcn_cvt_pk_fp8_f32(p2, p3, w, true);
                *(unsigned*)(Pw + low * 80 + u * 16 + q * 4) = w;
            }
        }

        // PV(j): acc2[tp] += V^T P^T (32x32x64, unit scales)
        {
            const unsigned char* Pr = &Pb[j & 1][0][0];
            __builtin_amdgcn_s_setprio(1);
#pragma unroll
            for (int tp = 0; tp < 2; tp++) {
                const unsigned char* pr = Pr + (tp * 2 + dsel) * 1280 + low * 80 + hi * 32;
                i32x8 pf;
                ((uint4*)&pf)[0] = *(const uint4*)pr;
                ((uint4*)&pf)[1] = *(const uint4*)(pr + 16);
                acc2[tp] = __builtin_amdgcn_mfma_scale_f32_32x32x64_f8f6f4(
                    Vuse, pf, acc2[tp], 0, 0, 0, 127, 0, 127);
            }
            __builtin_amdgcn_s_setprio(0);
        }

        // issue V(j+2) into the buffer just consumed (no copy, no wait here)
        if (j + 2 < 64) {
            const uint2* Vs = Vq + (size_t)(j + 2) * 2048;
            long* dqw = (long*)&Vuse;
#pragma unroll
            for (int ss = 0; ss < 4; ss++)
                dqw[ss] = *(const long*)(Vs + dt * 64 + ss * 16);
        }
        p_barrier();
    };

    for (int i = 0; i < 64; i += 2) {
        step(i, vA);
        step(i + 1, vB);
    }

    // ---- l: reduce across quads, publish per n ----
    if (isQK) {
        lacc += __shfl_xor(lacc, 16, 64);
        lacc += __shfl_xor(lacc, 32, 64);
        if (lane < 16)
            l_sh[wave * 16 + low] = lacc;
    }

    // ---- O^T -> bf16 LDS (row = n, col = d/2; stride 129 == 1 mod 32) ----
    // C layout: n = tp*32 + (lane&31), d = wave*32 + (r&3) + 8*(r>>2) + 4*hi.
#pragma unroll
    for (int tp = 0; tp < 2; tp++)
#pragma unroll
        for (int r = 0; r < 16; r += 2) {
            int col16 = wave * 16 + ((r >> 1) & 1) + 4 * (r >> 2) + 2 * hi;
            Ot[(tp * 32 + l31) * 129 + col16] = bfpk(acc2[tp][r], acc2[tp][r + 1]);
        }
    __syncthreads();

    // ---- out[b][d][n0+lane] = gamma * O/l + x, 256 B coalesced rows ----
    {
        float gm = gamma[0];
        float rinv = gm / l_sh[lane];      // lane == n-within-block
        size_t nb = ((size_t)(b * 256 + wave * 32)) * 4096 + g * 64 + lane;
#pragma unroll 4
        for (int j = 0; j < 32; j++) {
            unsigned pk = Ot[lane * 129 + wave * 16 + (j >> 1)];
            unsigned bits = (j & 1) ? (pk & 0xffff0000u) : (pk << 16);
            float o = __uint_as_float(bits);
            size_t idx = nb + (size_t)j * 4096;
            out[idx] = o * rinv + x[idx];
        }
    }
}

// ---------------------------------------------------------------------------
extern "C" void kernel_launch(void* const* d_in, const int* in_sizes, int n_in,
                              void* d_out, int out_size, void* d_ws, size_t ws_size,
                              hipStream_t stream) {
    const float* x     = (const float*)d_in[0];
    const float* ctx   = (const float*)d_in[1];
    const float* Wq    = (const float*)d_in[2];
    const float* bq    = (const float*)d_in[3];
    const float* Wk    = (const float*)d_in[4];
    const float* bk    = (const float*)d_in[5];
    const float* Wv    = (const float*)d_in[6];
    const float* bv    = (const float*)d_in[7];
    const float* gamma = (const float*)d_in[8];
    float* out = (float*)d_out;

    // ws: Qf 1M | Kf 1M | Vf 4.2M | Wqf/Wkf 16K | Wvf 128K
    unsigned short* Qf = (unsigned short*)d_ws;
    unsigned short* Kf = Qf + (size_t)B_ * N_ * 32;
    unsigned char*  Vf = (unsigned char*)(Kf + (size_t)B_ * M_ * 32);
    uint4* Wqf = (uint4*)(Vf + (size_t)B_ * M_ * C_);
    uint4* Wkf = Wqf + 16 * 64;
    uint4* Wvf = Wkf + 16 * 64;

    prep<<<40, 256, 0, stream>>>(Wq, Wk, Wv, Wqf, Wkf, Wvf);
    fused_proj<<<512, 256, 0, stream>>>(x, ctx, Wqf, Wkf, Wvf, bq, bk, bv, Qf, Kf, Vf);
    attn<<<256, 512, 0, stream>>>(Qf, Kf, Vf, x, gamma, out);
}